// Round 2
// baseline (1235.377 us; speedup 1.0000x reference)
//
#include <hip/hip_runtime.h>
#include <hip/hip_bf16.h>

#define N_NODES 100000
#define NPAD    100096          // 782 * 128
#define NRB     782
#define E_EDGES 1600000
#define NBLK_SCAN 98

typedef unsigned int   uint;
typedef unsigned short ushort;
typedef __attribute__((ext_vector_type(8))) short bfx8;   // 8 bf16 (4 VGPRs)
typedef __attribute__((ext_vector_type(4))) float fx4;

__device__ __forceinline__ float bf2f(ushort u) {
    return __uint_as_float(((uint)u) << 16);
}
__device__ __forceinline__ ushort f2bf(float f) {
    uint x = __float_as_uint(f);
    return (ushort)((x + 0x7FFFu + ((x >> 16) & 1u)) >> 16);   // RNE
}
__device__ __forceinline__ float gelu_erf(float x) {
    return 0.5f * x * (1.0f + erff(x * 0.70710678118654752f));
}
__device__ __forceinline__ float wave_sum(float v) {
    #pragma unroll
    for (int m = 1; m < 64; m <<= 1) v += __shfl_xor(v, m, 64);
    return v;
}

// ---------------- graph prep ----------------
__global__ void k_deg(const int* __restrict__ src, const int* __restrict__ dst,
                      int* __restrict__ outc, int* __restrict__ inc)
{
    int e = blockIdx.x * 256 + threadIdx.x;
    if (e < E_EDGES) {
        atomicAdd(&outc[src[e]], 1);
        atomicAdd(&inc[dst[e]], 1);
    }
}

__global__ void k_scales(const int* __restrict__ outc, const int* __restrict__ inc,
                         float* __restrict__ oscale, float* __restrict__ ininv)
{
    int r = blockIdx.x * 256 + threadIdx.x;
    if (r < NPAD) {
        oscale[r] = rsqrtf((float)max(outc[r], 1));
        ininv[r]  = rsqrtf((float)max(inc[r], 1));
    }
}

__global__ void k_scan1(const int* __restrict__ inc, int* __restrict__ coff, int* __restrict__ btot)
{
    __shared__ int a[1024], bsh[1024];
    int t = threadIdx.x;
    int i = blockIdx.x * 1024 + t;
    a[t] = (i < N_NODES) ? inc[i] : 0;
    __syncthreads();
    int* s = a; int* d = bsh;
    for (int dd = 1; dd < 1024; dd <<= 1) {
        int v = s[t] + ((t >= dd) ? s[t - dd] : 0);
        d[t] = v;
        __syncthreads();
        int* tmp = s; s = d; d = tmp;
    }
    if (i < N_NODES) coff[i + 1] = s[t];
    if (t == 1023) btot[blockIdx.x] = s[t];
}

__global__ void k_scan2(int* __restrict__ btot)
{
    __shared__ int a[128], bsh[128];
    int t = threadIdx.x;
    a[t] = (t < NBLK_SCAN) ? btot[t] : 0;
    __syncthreads();
    int* s = a; int* d = bsh;
    for (int dd = 1; dd < 128; dd <<= 1) {
        int v = s[t] + ((t >= dd) ? s[t - dd] : 0);
        d[t] = v;
        __syncthreads();
        int* tmp = s; s = d; d = tmp;
    }
    if (t < NBLK_SCAN) btot[t] = s[t];
}

__global__ void k_scan3(int* __restrict__ coff, const int* __restrict__ btot)
{
    int i = blockIdx.x * 256 + threadIdx.x;
    if (i == 0) coff[0] = 0;
    if (i < N_NODES) {
        int blk = i >> 10;
        if (blk > 0) coff[i + 1] += btot[blk - 1];
    }
}

__global__ void k_fill(const int* __restrict__ src, const int* __restrict__ dst,
                       const int* __restrict__ coff, int* __restrict__ cur, int* __restrict__ eidx)
{
    int e = blockIdx.x * 256 + threadIdx.x;
    if (e < E_EDGES) {
        int d = dst[e];
        int p = coff[d] + atomicAdd(&cur[d], 1);
        eidx[p] = src[e];
    }
}

// one wave per dst row: agg[r,:] = sum_{e: dst=r} x[src_e,:] * oscale[src_e], bf16 out
__global__ void k_agg(const int* __restrict__ off, const int* __restrict__ eidx,
                      const float* __restrict__ x, const float* __restrict__ oscale,
                      ushort* __restrict__ agg)
{
    int wid = threadIdx.x >> 6, lane = threadIdx.x & 63;
    int r = blockIdx.x * 4 + wid;
    if (r >= NPAD) return;
    float a0 = 0.f, a1 = 0.f;
    if (r < N_NODES) {
        int s = off[r], e = off[r + 1];
        for (int i = s; i < e; ++i) {
            int sv = eidx[i];
            float sc = oscale[sv];
            float2 v = *(const float2*)(x + (size_t)sv * 128 + lane * 2);
            a0 += v.x * sc;
            a1 += v.y * sc;
        }
    }
    uint o = (uint)f2bf(a0) | ((uint)f2bf(a1) << 16);
    *(uint*)(agg + (size_t)r * 128 + lane * 2) = o;
}

// transpose+convert weight [K,M] f32 -> [M,K] bf16
__global__ void k_wT(const float* __restrict__ W, int K, int M, ushort* __restrict__ Wt)
{
    int id = blockIdx.x * 256 + threadIdx.x;
    if (id < K * M) {
        int m = id / K, k = id - m * K;
        Wt[id] = f2bf(W[(size_t)k * M + m]);
    }
}

// ---------------- GEMM (out-of-place): C[NPAD,M] = A[NPAD,K] @ Bt[M,K]^T ----------------
// EPI: 0 = rowscale*acc + bias, 1 = gelu(acc+bias), 2 = acc+bias
template <int EPI>
__global__ __launch_bounds__(256) void k_gemm(
    const ushort* __restrict__ A, const ushort* __restrict__ Bt,
    ushort* __restrict__ C, int K, int M,
    const float* __restrict__ bias, const float* __restrict__ rowscale)
{
    __shared__ __align__(16) ushort As[128 * 64];
    __shared__ __align__(16) ushort Bs[128 * 64];
    char* AsB = (char*)As;
    char* BsB = (char*)Bs;

    const int nCB = M >> 7;
    const int cb = blockIdx.x % nCB;
    const int rb = blockIdx.x / nCB;
    const int tid = threadIdx.x;
    const int lane = tid & 63;
    const int wid = tid >> 6;
    const int m0 = (wid >> 1) * 64;
    const int n0 = (wid & 1) * 64;
    const int frl = lane & 15;
    const int kg = lane >> 4;   // 0..3

    fx4 acc[4][4] = {};

    const ushort* Arow0 = A + (size_t)(rb * 128) * K;
    const ushort* Brow0 = Bt + (size_t)(cb * 128) * K;

    for (int kb = 0; kb < K; kb += 64) {
        #pragma unroll
        for (int c = 0; c < 4; ++c) {
            int b = c * 4096 + tid * 16;     // linear byte in 16KB tile
            int row = b >> 7;                // 128B per row (64 bf16)
            int cib = b & 127;
            int swz = b ^ ((row & 7) << 4);  // XOR-swizzle 16B slots
            *(bfx8*)(AsB + swz) = *(const bfx8*)((const char*)(Arow0 + (size_t)row * K + kb) + cib);
            *(bfx8*)(BsB + swz) = *(const bfx8*)((const char*)(Brow0 + (size_t)row * K + kb) + cib);
        }
        __syncthreads();
        #pragma unroll
        for (int kk = 0; kk < 2; ++kk) {
            bfx8 av[4], bv[4];
            #pragma unroll
            for (int i = 0; i < 4; ++i) {
                int ar = m0 + i * 16 + frl;
                int ab = (ar * 128 + kk * 64 + kg * 16) ^ ((ar & 7) << 4);
                av[i] = *(const bfx8*)(AsB + ab);
                int br = n0 + i * 16 + frl;
                int bb = (br * 128 + kk * 64 + kg * 16) ^ ((br & 7) << 4);
                bv[i] = *(const bfx8*)(BsB + bb);
            }
            #pragma unroll
            for (int i = 0; i < 4; ++i)
                #pragma unroll
                for (int j = 0; j < 4; ++j)
                    acc[i][j] = __builtin_amdgcn_mfma_f32_16x16x32_bf16(av[i], bv[j], acc[i][j], 0, 0, 0);
        }
        __syncthreads();
    }

    #pragma unroll
    for (int j = 0; j < 4; ++j) {
        int col = cb * 128 + n0 + j * 16 + frl;
        float bcol = bias[col];
        #pragma unroll
        for (int i = 0; i < 4; ++i) {
            int rbase = rb * 128 + m0 + i * 16 + kg * 4;
            #pragma unroll
            for (int r = 0; r < 4; ++r) {
                float v = acc[i][j][r];
                int row = rbase + r;
                if (EPI == 0)      v = v * rowscale[row] + bcol;
                else if (EPI == 1) v = gelu_erf(v + bcol);
                else               v = v + bcol;
                C[(size_t)row * M + col] = f2bf(v);
            }
        }
    }
}

// ---------------- GEMM (in-place): AC[NPAD,M=KT] = epi(AC @ Bt^T) ----------------
// Full 128-row x KT A-tile staged in LDS before any global write; rows are
// block-exclusive so in-place is safe.
template <int KT, int EPI>
__global__ __launch_bounds__(256) void k_gemm_ip(
    ushort* __restrict__ AC, const ushort* __restrict__ Bt, int M,
    const float* __restrict__ bias, const float* __restrict__ rowscale)
{
    __shared__ __align__(16) ushort As[128 * KT];
    __shared__ __align__(16) ushort Bs[128 * 64];
    char* AsB = (char*)As;
    char* BsB = (char*)Bs;
    const int RB = KT * 2;              // bytes per LDS A row
    const int tid = threadIdx.x;
    const int lane = tid & 63;
    const int wid = tid >> 6;
    const int m0 = (wid >> 1) * 64;
    const int n0 = (wid & 1) * 64;
    const int frl = lane & 15;
    const int kg = lane >> 4;
    const int rb = blockIdx.x;

    ushort* Arow0 = AC + (size_t)(rb * 128) * KT;
    #pragma unroll
    for (int c = 0; c < KT / 16; ++c) {
        int b = c * 4096 + tid * 16;
        int row = b / RB;
        int cib = b % RB;
        int swz = b ^ ((row & 7) << 4);
        *(bfx8*)(AsB + swz) = *(const bfx8*)((const char*)(Arow0 + (size_t)row * KT) + cib);
    }
    __syncthreads();

    for (int cb = 0; cb < (M >> 7); ++cb) {
        const ushort* Brow0 = Bt + (size_t)(cb * 128) * KT;
        fx4 acc[4][4] = {};
        for (int kb = 0; kb < KT; kb += 64) {
            #pragma unroll
            for (int c = 0; c < 4; ++c) {
                int b = c * 4096 + tid * 16;
                int row = b >> 7;
                int cib = b & 127;
                int swz = b ^ ((row & 7) << 4);
                *(bfx8*)(BsB + swz) = *(const bfx8*)((const char*)(Brow0 + (size_t)row * KT + kb) + cib);
            }
            __syncthreads();
            #pragma unroll
            for (int kk = 0; kk < 2; ++kk) {
                bfx8 av[4], bv[4];
                #pragma unroll
                for (int i = 0; i < 4; ++i) {
                    int ar = m0 + i * 16 + frl;
                    int ab = (ar * RB + kb * 2 + kk * 64 + kg * 16) ^ ((ar & 7) << 4);
                    av[i] = *(const bfx8*)(AsB + ab);
                    int br = n0 + i * 16 + frl;
                    int bb = (br * 128 + kk * 64 + kg * 16) ^ ((br & 7) << 4);
                    bv[i] = *(const bfx8*)(BsB + bb);
                }
                #pragma unroll
                for (int i = 0; i < 4; ++i)
                    #pragma unroll
                    for (int j = 0; j < 4; ++j)
                        acc[i][j] = __builtin_amdgcn_mfma_f32_16x16x32_bf16(av[i], bv[j], acc[i][j], 0, 0, 0);
            }
            __syncthreads();
        }
        #pragma unroll
        for (int j = 0; j < 4; ++j) {
            int col = cb * 128 + n0 + j * 16 + frl;
            float bcol = bias[col];
            #pragma unroll
            for (int i = 0; i < 4; ++i) {
                int rbase = rb * 128 + m0 + i * 16 + kg * 4;
                #pragma unroll
                for (int r = 0; r < 4; ++r) {
                    float v = acc[i][j][r];
                    int row = rbase + r;
                    if (EPI == 0)      v = v * rowscale[row] + bcol;
                    else if (EPI == 1) v = gelu_erf(v + bcol);
                    else               v = v + bcol;
                    AC[(size_t)row * M + col] = f2bf(v);
                }
            }
        }
    }
}

// in-place LayerNorm over 512 cols, one wave per row
__global__ void k_ln(ushort* __restrict__ f, const float* __restrict__ g, const float* __restrict__ b)
{
    int wid = threadIdx.x >> 6, lane = threadIdx.x & 63;
    int r = blockIdx.x * 4 + wid;
    if (r >= N_NODES) return;
    ushort* row = f + (size_t)r * 512;
    bfx8 raw = *(const bfx8*)(row + lane * 8);
    float v[8];
    float s = 0.f, q = 0.f;
    #pragma unroll
    for (int i = 0; i < 8; ++i) {
        v[i] = bf2f((ushort)raw[i]);
        s += v[i]; q += v[i] * v[i];
    }
    s = wave_sum(s); q = wave_sum(q);
    float mean = s * (1.f / 512.f);
    float var = q * (1.f / 512.f) - mean * mean;
    float sc = rsqrtf(var + 1e-5f);
    float4 g0 = *(const float4*)(g + lane * 8), g1 = *(const float4*)(g + lane * 8 + 4);
    float4 b0 = *(const float4*)(b + lane * 8), b1 = *(const float4*)(b + lane * 8 + 4);
    float gg[8] = {g0.x, g0.y, g0.z, g0.w, g1.x, g1.y, g1.z, g1.w};
    float bb[8] = {b0.x, b0.y, b0.z, b0.w, b1.x, b1.y, b1.z, b1.w};
    bfx8 o;
    #pragma unroll
    for (int i = 0; i < 8; ++i) o[i] = (short)f2bf((v[i] - mean) * sc * gg[i] + bb[i]);
    *(bfx8*)(row + lane * 8) = o;
}

// coalesced column sums / sumsq over rows < N_NODES
template <int M>
__global__ void k_bnstat(const ushort* __restrict__ X,
                         float* __restrict__ sum, float* __restrict__ sqs)
{
    const int CP = M >> 1;          // col-pairs per row
    const int RPB = 256 / CP;       // rows handled per block-iteration
    int t = threadIdx.x;
    int cp = t % CP;
    int rsub = t / CP;
    float s0 = 0.f, s1 = 0.f, q0 = 0.f, q1 = 0.f;
    for (int r = blockIdx.x * RPB + rsub; r < N_NODES; r += gridDim.x * RPB) {
        uint u = *(const uint*)(X + (size_t)r * M + cp * 2);
        float v0 = bf2f((ushort)(u & 0xffffu));
        float v1 = bf2f((ushort)(u >> 16));
        s0 += v0; q0 += v0 * v0;
        s1 += v1; q1 += v1 * v1;
    }
    atomicAdd(&sum[cp * 2], s0);
    atomicAdd(&sum[cp * 2 + 1], s1);
    atomicAdd(&sqs[cp * 2], q0);
    atomicAdd(&sqs[cp * 2 + 1], q1);
}

// fold BN(prev-layer cols) into next weight
__global__ void k_fold(const float* __restrict__ W, const float* __restrict__ bw,
                       const float* __restrict__ g, const float* __restrict__ bb,
                       const float* __restrict__ sum, const float* __restrict__ sqs,
                       int K, int M, ushort* __restrict__ WtO, float* __restrict__ bO)
{
    int wid = threadIdx.x >> 6, lane = threadIdx.x & 63;
    int m = blockIdx.x * 4 + wid;
    if (m >= M) return;
    float acc = 0.f;
    for (int k = lane; k < K; k += 64) {
        float mean = sum[k] * (1.f / (float)N_NODES);
        float var = sqs[k] * (1.f / (float)N_NODES) - mean * mean;
        float s = g[k] * rsqrtf(var + 1e-5f);
        float t = bb[k] - mean * s;
        float w = W[(size_t)k * M + m];
        WtO[(size_t)m * K + k] = f2bf(w * s);
        acc += t * w;
    }
    acc = wave_sum(acc);
    if (lane == 0) bO[m] = bw[m] + acc;
}

// out[r] = dot(m3[r,:128], w4) + b4
__global__ void k_out(const ushort* __restrict__ m3, const ushort* __restrict__ w4,
                      const float* __restrict__ b4, float* __restrict__ out)
{
    int wid = threadIdx.x >> 6, lane = threadIdx.x & 63;
    int r = blockIdx.x * 4 + wid;
    if (r >= N_NODES) return;
    uint u = *(const uint*)(m3 + (size_t)r * 128 + lane * 2);
    uint w = *(const uint*)(w4 + lane * 2);
    float acc = bf2f((ushort)(u & 0xffffu)) * bf2f((ushort)(w & 0xffffu))
              + bf2f((ushort)(u >> 16)) * bf2f((ushort)(w >> 16));
    acc = wave_sum(acc);
    if (lane == 0) out[r] = acc + b4[0];
}

extern "C" void kernel_launch(void* const* d_in, const int* in_sizes, int n_in,
                              void* d_out, int out_size, void* d_ws, size_t ws_size,
                              hipStream_t stream)
{
    const float* x     = (const float*)d_in[0];
    const int*   src   = (const int*)d_in[1];
    const int*   dst   = (const int*)d_in[2];
    const float* gcn_w = (const float*)d_in[3];
    const float* gcn_b = (const float*)d_in[4];
    const float* ff_w1 = (const float*)d_in[5];
    const float* ff_b1 = (const float*)d_in[6];
    const float* ln_g  = (const float*)d_in[7];
    const float* ln_b  = (const float*)d_in[8];
    const float* ff_w2 = (const float*)d_in[9];
    const float* ff_b2 = (const float*)d_in[10];
    const float* fc1_w = (const float*)d_in[11];
    const float* fc1_b = (const float*)d_in[12];
    const float* bn1_g = (const float*)d_in[13];
    const float* bn1_b = (const float*)d_in[14];
    const float* fc2_w = (const float*)d_in[15];
    const float* fc2_b = (const float*)d_in[16];
    const float* bn2_g = (const float*)d_in[17];
    const float* bn2_b = (const float*)d_in[18];
    const float* fc3_w = (const float*)d_in[19];
    const float* fc3_b = (const float*)d_in[20];
    const float* bn3_g = (const float*)d_in[21];
    const float* bn3_b = (const float*)d_in[22];
    const float* fc4_w = (const float*)d_in[23];
    const float* fc4_b = (const float*)d_in[24];
    float* out = (float*)d_out;
    (void)in_sizes; (void)n_in; (void)out_size; (void)ws_size;

    char* p = (char*)d_ws;
    auto alloc = [&](size_t bytes) -> char* {
        char* r = p;
        p += (bytes + 255) & ~(size_t)255;
        return r;
    };
    // total ≈ 138 MB
    int*    outc   = (int*)alloc((size_t)NPAD * 4);
    int*    inc    = (int*)alloc((size_t)NPAD * 4);
    int*    cur    = (int*)alloc((size_t)NPAD * 4);
    int*    coff   = (int*)alloc(((size_t)NPAD + 1) * 4);
    int*    btot   = (int*)alloc(128 * 4);
    int*    eidx   = (int*)alloc((size_t)E_EDGES * 4);
    float*  oscale = (float*)alloc((size_t)NPAD * 4);
    float*  ininv  = (float*)alloc((size_t)NPAD * 4);
    float*  bns    = (float*)alloc(6 * 512 * 4);
    float*  b2p    = (float*)alloc(512 * 4);
    float*  b3p    = (float*)alloc(128 * 4);
    float*  b4p    = (float*)alloc(4);
    ushort* gwT    = (ushort*)alloc(128 * 128 * 2);
    ushort* ff1T   = (ushort*)alloc(512 * 128 * 2);
    ushort* ff2T   = (ushort*)alloc(128 * 512 * 2);
    ushort* fc1T   = (ushort*)alloc(512 * 128 * 2);
    ushort* fc2T   = (ushort*)alloc(512 * 512 * 2);
    ushort* fc3T   = (ushort*)alloc(128 * 512 * 2);
    ushort* w4t    = (ushort*)alloc(128 * 2);
    ushort* buf1   = (ushort*)alloc((size_t)NPAD * 128 * 2);  // agg -> h(ip) -> h2 -> m3
    ushort* bufC   = (ushort*)alloc((size_t)NPAD * 512 * 2);  // f(+LN) -> m1 -> m2(ip)

    float* bn1s = bns;
    float* bn1q = bns + 512;
    float* bn2s = bns + 1024;
    float* bn2q = bns + 1536;
    float* bn3s = bns + 2048;
    float* bn3q = bns + 2560;

    hipMemsetAsync(outc, 0, (size_t)NPAD * 4, stream);
    hipMemsetAsync(inc, 0, (size_t)NPAD * 4, stream);
    hipMemsetAsync(cur, 0, (size_t)NPAD * 4, stream);
    hipMemsetAsync(bns, 0, 6 * 512 * 4, stream);

    k_deg<<<E_EDGES / 256, 256, 0, stream>>>(src, dst, outc, inc);
    k_scales<<<NPAD / 256, 256, 0, stream>>>(outc, inc, oscale, ininv);
    k_scan1<<<NBLK_SCAN, 1024, 0, stream>>>(inc, coff, btot);
    k_scan2<<<1, 128, 0, stream>>>(btot);
    k_scan3<<<(N_NODES + 255) / 256, 256, 0, stream>>>(coff, btot);
    k_fill<<<E_EDGES / 256, 256, 0, stream>>>(src, dst, coff, cur, eidx);
    k_agg<<<NPAD / 4, 256, 0, stream>>>(coff, eidx, x, oscale, buf1);

    k_wT<<<(128 * 128) / 256, 256, 0, stream>>>(gcn_w, 128, 128, gwT);
    k_wT<<<(128 * 512) / 256, 256, 0, stream>>>(ff_w1, 128, 512, ff1T);
    k_wT<<<(512 * 128) / 256, 256, 0, stream>>>(ff_w2, 512, 128, ff2T);
    k_wT<<<(128 * 512) / 256, 256, 0, stream>>>(fc1_w, 128, 512, fc1T);

    // GCN: h = (agg @ gcn_w) * ininv + gcn_b   (in-place in buf1)
    k_gemm_ip<128, 0><<<NRB, 256, 0, stream>>>(buf1, gwT, 128, gcn_b, ininv);
    // f = gelu(h @ ff_w1 + ff_b1)
    k_gemm<1><<<4 * NRB, 256, 0, stream>>>(buf1, ff1T, bufC, 128, 512, ff_b1, nullptr);
    k_ln<<<N_NODES / 4, 256, 0, stream>>>(bufC, ln_g, ln_b);
    // h2 = f @ ff_w2 + ff_b2
    k_gemm<2><<<NRB, 256, 0, stream>>>(bufC, ff2T, buf1, 512, 128, ff_b2, nullptr);
    // m1 = gelu(h2 @ fc1_w + fc1_b)
    k_gemm<1><<<4 * NRB, 256, 0, stream>>>(buf1, fc1T, bufC, 128, 512, fc1_b, nullptr);
    k_bnstat<512><<<256, 256, 0, stream>>>(bufC, bn1s, bn1q);
    k_fold<<<512 / 4, 256, 0, stream>>>(fc2_w, fc2_b, bn1_g, bn1_b, bn1s, bn1q, 512, 512, fc2T, b2p);
    // m2 = gelu(bn1(m1) @ fc2_w + fc2_b)   (in-place in bufC)
    k_gemm_ip<512, 1><<<NRB, 256, 0, stream>>>(bufC, fc2T, 512, b2p, nullptr);
    k_bnstat<512><<<256, 256, 0, stream>>>(bufC, bn2s, bn2q);
    k_fold<<<128 / 4, 256, 0, stream>>>(fc3_w, fc3_b, bn2_g, bn2_b, bn2s, bn2q, 512, 128, fc3T, b3p);
    // m3 = gelu(bn2(m2) @ fc3_w + fc3_b)
    k_gemm<1><<<NRB, 256, 0, stream>>>(bufC, fc3T, buf1, 512, 128, b3p, nullptr);
    k_bnstat<128><<<256, 256, 0, stream>>>(buf1, bn3s, bn3q);
    k_fold<<<1, 256, 0, stream>>>(fc4_w, fc4_b, bn3_g, bn3_b, bn3s, bn3q, 128, 1, w4t, b4p);
    k_out<<<N_NODES / 4, 256, 0, stream>>>(buf1, w4t, b4p, out);
}

// Round 3
// 1192.581 us; speedup vs baseline: 1.0359x; 1.0359x over previous
//
#include <hip/hip_runtime.h>
#include <hip/hip_bf16.h>

#define N_NODES 100000
#define NPAD    100096          // 782 * 128
#define NRB     782
#define E_EDGES 1600000
#define NBLK_SCAN 98

typedef unsigned int   uint;
typedef unsigned short ushort;
typedef __attribute__((ext_vector_type(8))) short bfx8;   // 8 bf16 (4 VGPRs)
typedef __attribute__((ext_vector_type(4))) float fx4;

__device__ __forceinline__ float bf2f(ushort u) {
    return __uint_as_float(((uint)u) << 16);
}
__device__ __forceinline__ ushort f2bf(float f) {
    uint x = __float_as_uint(f);
    return (ushort)((x + 0x7FFFu + ((x >> 16) & 1u)) >> 16);   // RNE
}
__device__ __forceinline__ float gelu_erf(float x) {
    return 0.5f * x * (1.0f + erff(x * 0.70710678118654752f));
}
__device__ __forceinline__ float wave_sum(float v) {
    #pragma unroll
    for (int m = 1; m < 64; m <<= 1) v += __shfl_xor(v, m, 64);
    return v;
}

// ---------------- graph prep ----------------
__global__ void k_deg(const int* __restrict__ src, const int* __restrict__ dst,
                      int* __restrict__ outc, int* __restrict__ inc)
{
    int e = blockIdx.x * 256 + threadIdx.x;
    if (e < E_EDGES) {
        atomicAdd(&outc[src[e]], 1);
        atomicAdd(&inc[dst[e]], 1);
    }
}

__global__ void k_scales(const int* __restrict__ outc, const int* __restrict__ inc,
                         float* __restrict__ oscale, float* __restrict__ ininv)
{
    int r = blockIdx.x * 256 + threadIdx.x;
    if (r < NPAD) {
        oscale[r] = rsqrtf((float)max(outc[r], 1));
        ininv[r]  = rsqrtf((float)max(inc[r], 1));
    }
}

__global__ void k_scan1(const int* __restrict__ inc, int* __restrict__ coff, int* __restrict__ btot)
{
    __shared__ int a[1024], bsh[1024];
    int t = threadIdx.x;
    int i = blockIdx.x * 1024 + t;
    a[t] = (i < N_NODES) ? inc[i] : 0;
    __syncthreads();
    int* s = a; int* d = bsh;
    for (int dd = 1; dd < 1024; dd <<= 1) {
        int v = s[t] + ((t >= dd) ? s[t - dd] : 0);
        d[t] = v;
        __syncthreads();
        int* tmp = s; s = d; d = tmp;
    }
    if (i < N_NODES) coff[i + 1] = s[t];
    if (t == 1023) btot[blockIdx.x] = s[t];
}

__global__ void k_scan2(int* __restrict__ btot)
{
    __shared__ int a[128], bsh[128];
    int t = threadIdx.x;
    a[t] = (t < NBLK_SCAN) ? btot[t] : 0;
    __syncthreads();
    int* s = a; int* d = bsh;
    for (int dd = 1; dd < 128; dd <<= 1) {
        int v = s[t] + ((t >= dd) ? s[t - dd] : 0);
        d[t] = v;
        __syncthreads();
        int* tmp = s; s = d; d = tmp;
    }
    if (t < NBLK_SCAN) btot[t] = s[t];
}

__global__ void k_scan3(int* __restrict__ coff, const int* __restrict__ btot)
{
    int i = blockIdx.x * 256 + threadIdx.x;
    if (i == 0) coff[0] = 0;
    if (i < N_NODES) {
        int blk = i >> 10;
        if (blk > 0) coff[i + 1] += btot[blk - 1];
    }
}

__global__ void k_fill(const int* __restrict__ src, const int* __restrict__ dst,
                       const int* __restrict__ coff, int* __restrict__ cur, int* __restrict__ eidx)
{
    int e = blockIdx.x * 256 + threadIdx.x;
    if (e < E_EDGES) {
        int d = dst[e];
        int p = coff[d] + atomicAdd(&cur[d], 1);
        eidx[p] = src[e];
    }
}

// xh[r,:] = bf16(x[r,:] * oscale[r])
__global__ void k_xhat(const float* __restrict__ x, const float* __restrict__ oscale,
                       ushort* __restrict__ xh)
{
    size_t i = (size_t)blockIdx.x * 256 + threadIdx.x;
    size_t e0 = i * 4;
    int row = (int)(e0 >> 7);
    uint2 o;
    if (row < N_NODES) {
        float4 v = *(const float4*)(x + e0);
        float s = oscale[row];
        o.x = (uint)f2bf(v.x * s) | ((uint)f2bf(v.y * s) << 16);
        o.y = (uint)f2bf(v.z * s) | ((uint)f2bf(v.w * s) << 16);
    } else {
        o.x = 0u; o.y = 0u;
    }
    *(uint2*)(xh + e0) = o;
}

// one wave per dst row: agg[r,:] = sum_{e: dst=r} xh[src_e,:]
__global__ void k_agg(const int* __restrict__ off, const int* __restrict__ eidx,
                      const ushort* __restrict__ xh, ushort* __restrict__ agg)
{
    int wid = threadIdx.x >> 6, lane = threadIdx.x & 63;
    int r = blockIdx.x * 4 + wid;
    if (r >= NPAD) return;
    float a0 = 0.f, a1 = 0.f;
    if (r < N_NODES) {
        int s = off[r], e = off[r + 1];
        for (int i = s; i < e; ++i) {
            int sv = eidx[i];
            uint u = *(const uint*)(xh + (size_t)sv * 128 + lane * 2);
            a0 += bf2f((ushort)(u & 0xffffu));
            a1 += bf2f((ushort)(u >> 16));
        }
    }
    uint o = (uint)f2bf(a0) | ((uint)f2bf(a1) << 16);
    *(uint*)(agg + (size_t)r * 128 + lane * 2) = o;
}

// transpose+convert weight [K,M] f32 -> [M,K] bf16
__global__ void k_wT(const float* __restrict__ W, int K, int M, ushort* __restrict__ Wt)
{
    int id = blockIdx.x * 256 + threadIdx.x;
    if (id < K * M) {
        int m = id / K, k = id - m * K;
        Wt[id] = f2bf(W[(size_t)k * M + m]);
    }
}

// ---------------- GEMM: C[rows,M] = A[rows,K] @ Bt[M,K]^T, bf16 MFMA ----------------
// EPI: 0 = rowscale*acc + bias, 1 = gelu(acc+bias), 2 = acc+bias
// rows == gridDim.x/ (M>>7) * 128; rowscale indexed with rsoff + row.
template <int EPI>
__global__ __launch_bounds__(256, 4) void k_gemm(
    const ushort* __restrict__ A, const ushort* __restrict__ Bt,
    ushort* __restrict__ C, int K, int M,
    const float* __restrict__ bias, const float* __restrict__ rowscale)
{
    __shared__ __align__(16) ushort As[128 * 64];
    __shared__ __align__(16) ushort Bs[128 * 64];
    char* AsB = (char*)As;
    char* BsB = (char*)Bs;

    const int nCB = M >> 7;
    const int cb = blockIdx.x % nCB;
    const int rb = blockIdx.x / nCB;
    const int tid = threadIdx.x;
    const int lane = tid & 63;
    const int wid = tid >> 6;
    const int m0 = (wid >> 1) * 64;
    const int n0 = (wid & 1) * 64;
    const int frl = lane & 15;
    const int kg = lane >> 4;   // 0..3

    fx4 acc[4][4] = {};

    const ushort* Arow0 = A + (size_t)(rb * 128) * K;
    const ushort* Brow0 = Bt + (size_t)(cb * 128) * K;

    for (int kb = 0; kb < K; kb += 64) {
        #pragma unroll
        for (int c = 0; c < 4; ++c) {
            int b = c * 4096 + tid * 16;     // linear byte in 16KB tile
            int row = b >> 7;                // 128B per row (64 bf16)
            int cib = b & 127;
            int swz = b ^ ((row & 7) << 4);  // XOR-swizzle 16B slots
            *(bfx8*)(AsB + swz) = *(const bfx8*)((const char*)(Arow0 + (size_t)row * K + kb) + cib);
            *(bfx8*)(BsB + swz) = *(const bfx8*)((const char*)(Brow0 + (size_t)row * K + kb) + cib);
        }
        __syncthreads();
        #pragma unroll
        for (int kk = 0; kk < 2; ++kk) {
            bfx8 av[4], bv[4];
            #pragma unroll
            for (int i = 0; i < 4; ++i) {
                int ar = m0 + i * 16 + frl;
                int ab = (ar * 128 + kk * 64 + kg * 16) ^ ((ar & 7) << 4);
                av[i] = *(const bfx8*)(AsB + ab);
                int br = n0 + i * 16 + frl;
                int bb = (br * 128 + kk * 64 + kg * 16) ^ ((br & 7) << 4);
                bv[i] = *(const bfx8*)(BsB + bb);
            }
            #pragma unroll
            for (int i = 0; i < 4; ++i)
                #pragma unroll
                for (int j = 0; j < 4; ++j)
                    acc[i][j] = __builtin_amdgcn_mfma_f32_16x16x32_bf16(av[i], bv[j], acc[i][j], 0, 0, 0);
        }
        __syncthreads();
    }

    #pragma unroll
    for (int j = 0; j < 4; ++j) {
        int col = cb * 128 + n0 + j * 16 + frl;
        float bcol = bias[col];
        #pragma unroll
        for (int i = 0; i < 4; ++i) {
            int rbase = rb * 128 + m0 + i * 16 + kg * 4;
            #pragma unroll
            for (int r = 0; r < 4; ++r) {
                float v = acc[i][j][r];
                int row = rbase + r;
                if (EPI == 0)      v = v * rowscale[row] + bcol;
                else if (EPI == 1) v = gelu_erf(v + bcol);
                else               v = v + bcol;
                C[(size_t)row * M + col] = f2bf(v);
            }
        }
    }
}

// in-place LayerNorm over 512 cols, one wave per row
__global__ void k_ln(ushort* __restrict__ f, const float* __restrict__ g, const float* __restrict__ b)
{
    int wid = threadIdx.x >> 6, lane = threadIdx.x & 63;
    int r = blockIdx.x * 4 + wid;
    if (r >= N_NODES) return;
    ushort* row = f + (size_t)r * 512;
    bfx8 raw = *(const bfx8*)(row + lane * 8);
    float v[8];
    float s = 0.f, q = 0.f;
    #pragma unroll
    for (int i = 0; i < 8; ++i) {
        v[i] = bf2f((ushort)raw[i]);
        s += v[i]; q += v[i] * v[i];
    }
    s = wave_sum(s); q = wave_sum(q);
    float mean = s * (1.f / 512.f);
    float var = q * (1.f / 512.f) - mean * mean;
    float sc = rsqrtf(var + 1e-5f);
    float4 g0 = *(const float4*)(g + lane * 8), g1 = *(const float4*)(g + lane * 8 + 4);
    float4 b0 = *(const float4*)(b + lane * 8), b1 = *(const float4*)(b + lane * 8 + 4);
    float gg[8] = {g0.x, g0.y, g0.z, g0.w, g1.x, g1.y, g1.z, g1.w};
    float bb[8] = {b0.x, b0.y, b0.z, b0.w, b1.x, b1.y, b1.z, b1.w};
    bfx8 o;
    #pragma unroll
    for (int i = 0; i < 8; ++i) o[i] = (short)f2bf((v[i] - mean) * sc * gg[i] + bb[i]);
    *(bfx8*)(row + lane * 8) = o;
}

// coalesced column sums / sumsq over rows < N_NODES
template <int M>
__global__ void k_bnstat(const ushort* __restrict__ X,
                         float* __restrict__ sum, float* __restrict__ sqs)
{
    const int CP = M >> 1;          // col-pairs per row
    const int RPB = 256 / CP;       // rows handled per block-iteration
    int t = threadIdx.x;
    int cp = t % CP;
    int rsub = t / CP;
    float s0 = 0.f, s1 = 0.f, q0 = 0.f, q1 = 0.f;
    for (int r = blockIdx.x * RPB + rsub; r < N_NODES; r += gridDim.x * RPB) {
        uint u = *(const uint*)(X + (size_t)r * M + cp * 2);
        float v0 = bf2f((ushort)(u & 0xffffu));
        float v1 = bf2f((ushort)(u >> 16));
        s0 += v0; q0 += v0 * v0;
        s1 += v1; q1 += v1 * v1;
    }
    atomicAdd(&sum[cp * 2], s0);
    atomicAdd(&sum[cp * 2 + 1], s1);
    atomicAdd(&sqs[cp * 2], q0);
    atomicAdd(&sqs[cp * 2 + 1], q1);
}

// fold BN(prev-layer cols) into next weight
__global__ void k_fold(const float* __restrict__ W, const float* __restrict__ bw,
                       const float* __restrict__ g, const float* __restrict__ bb,
                       const float* __restrict__ sum, const float* __restrict__ sqs,
                       int K, int M, ushort* __restrict__ WtO, float* __restrict__ bO)
{
    int wid = threadIdx.x >> 6, lane = threadIdx.x & 63;
    int m = blockIdx.x * 4 + wid;
    if (m >= M) return;
    float acc = 0.f;
    for (int k = lane; k < K; k += 64) {
        float mean = sum[k] * (1.f / (float)N_NODES);
        float var = sqs[k] * (1.f / (float)N_NODES) - mean * mean;
        float s = g[k] * rsqrtf(var + 1e-5f);
        float t = bb[k] - mean * s;
        float w = W[(size_t)k * M + m];
        WtO[(size_t)m * K + k] = f2bf(w * s);
        acc += t * w;
    }
    acc = wave_sum(acc);
    if (lane == 0) bO[m] = bw[m] + acc;
}

// out[r] = dot(m3[r,:128], w4) + b4
__global__ void k_out(const ushort* __restrict__ m3, const ushort* __restrict__ w4,
                      const float* __restrict__ b4, float* __restrict__ out)
{
    int wid = threadIdx.x >> 6, lane = threadIdx.x & 63;
    int r = blockIdx.x * 4 + wid;
    if (r >= N_NODES) return;
    uint u = *(const uint*)(m3 + (size_t)r * 128 + lane * 2);
    uint w = *(const uint*)(w4 + lane * 2);
    float acc = bf2f((ushort)(u & 0xffffu)) * bf2f((ushort)(w & 0xffffu))
              + bf2f((ushort)(u >> 16)) * bf2f((ushort)(w >> 16));
    acc = wave_sum(acc);
    if (lane == 0) out[r] = acc + b4[0];
}

extern "C" void kernel_launch(void* const* d_in, const int* in_sizes, int n_in,
                              void* d_out, int out_size, void* d_ws, size_t ws_size,
                              hipStream_t stream)
{
    const float* x     = (const float*)d_in[0];
    const int*   src   = (const int*)d_in[1];
    const int*   dst   = (const int*)d_in[2];
    const float* gcn_w = (const float*)d_in[3];
    const float* gcn_b = (const float*)d_in[4];
    const float* ff_w1 = (const float*)d_in[5];
    const float* ff_b1 = (const float*)d_in[6];
    const float* ln_g  = (const float*)d_in[7];
    const float* ln_b  = (const float*)d_in[8];
    const float* ff_w2 = (const float*)d_in[9];
    const float* ff_b2 = (const float*)d_in[10];
    const float* fc1_w = (const float*)d_in[11];
    const float* fc1_b = (const float*)d_in[12];
    const float* bn1_g = (const float*)d_in[13];
    const float* bn1_b = (const float*)d_in[14];
    const float* fc2_w = (const float*)d_in[15];
    const float* fc2_b = (const float*)d_in[16];
    const float* bn2_g = (const float*)d_in[17];
    const float* bn2_b = (const float*)d_in[18];
    const float* fc3_w = (const float*)d_in[19];
    const float* fc3_b = (const float*)d_in[20];
    const float* bn3_g = (const float*)d_in[21];
    const float* bn3_b = (const float*)d_in[22];
    const float* fc4_w = (const float*)d_in[23];
    const float* fc4_b = (const float*)d_in[24];
    float* out = (float*)d_out;
    (void)in_sizes; (void)n_in; (void)out_size; (void)ws_size;

    char* p = (char*)d_ws;
    auto alloc = [&](size_t bytes) -> char* {
        char* r = p;
        p += (bytes + 255) & ~(size_t)255;
        return r;
    };
    // total ≈ 138 MB (same as the passing round-2 layout)
    int*    outc   = (int*)alloc((size_t)NPAD * 4);
    int*    inc    = (int*)alloc((size_t)NPAD * 4);
    int*    cur    = (int*)alloc((size_t)NPAD * 4);
    int*    coff   = (int*)alloc(((size_t)NPAD + 1) * 4);
    int*    btot   = (int*)alloc(128 * 4);
    int*    eidx   = (int*)alloc((size_t)E_EDGES * 4);
    float*  oscale = (float*)alloc((size_t)NPAD * 4);
    float*  ininv  = (float*)alloc((size_t)NPAD * 4);
    float*  bns    = (float*)alloc(6 * 512 * 4);
    float*  b2p    = (float*)alloc(512 * 4);
    float*  b3p    = (float*)alloc(128 * 4);
    float*  b4p    = (float*)alloc(4);
    ushort* gwT    = (ushort*)alloc(128 * 128 * 2);
    ushort* ff1T   = (ushort*)alloc(512 * 128 * 2);
    ushort* ff2T   = (ushort*)alloc(128 * 512 * 2);
    ushort* fc1T   = (ushort*)alloc(512 * 128 * 2);
    ushort* fc2T   = (ushort*)alloc(512 * 512 * 2);
    ushort* fc3T   = (ushort*)alloc(128 * 512 * 2);
    ushort* w4t    = (ushort*)alloc(128 * 2);
    ushort* buf1   = (ushort*)alloc((size_t)NPAD * 128 * 2);  // h -> h2 -> fc2 tmp -> m3
    ushort* bufC   = (ushort*)alloc((size_t)NPAD * 512 * 2);  // xh+agg -> f(+LN) -> m1 -> m2

    ushort* xh  = bufC;                          // [NPAD,128] region 0
    ushort* agg = bufC + (size_t)NPAD * 128;     // [NPAD,128] region 1

    float* bn1s = bns;
    float* bn1q = bns + 512;
    float* bn2s = bns + 1024;
    float* bn2q = bns + 1536;
    float* bn3s = bns + 2048;
    float* bn3q = bns + 2560;

    hipMemsetAsync(outc, 0, (size_t)NPAD * 4, stream);
    hipMemsetAsync(inc, 0, (size_t)NPAD * 4, stream);
    hipMemsetAsync(cur, 0, (size_t)NPAD * 4, stream);
    hipMemsetAsync(bns, 0, 6 * 512 * 4, stream);

    k_deg<<<E_EDGES / 256, 256, 0, stream>>>(src, dst, outc, inc);
    k_scales<<<NPAD / 256, 256, 0, stream>>>(outc, inc, oscale, ininv);
    k_scan1<<<NBLK_SCAN, 1024, 0, stream>>>(inc, coff, btot);
    k_scan2<<<1, 128, 0, stream>>>(btot);
    k_scan3<<<(N_NODES + 255) / 256, 256, 0, stream>>>(coff, btot);
    k_fill<<<E_EDGES / 256, 256, 0, stream>>>(src, dst, coff, cur, eidx);
    k_xhat<<<(NPAD / 256) * 32, 256, 0, stream>>>(x, oscale, xh);
    k_agg<<<NPAD / 4, 256, 0, stream>>>(coff, eidx, xh, agg);

    k_wT<<<(128 * 128) / 256, 256, 0, stream>>>(gcn_w, 128, 128, gwT);
    k_wT<<<(128 * 512) / 256, 256, 0, stream>>>(ff_w1, 128, 512, ff1T);
    k_wT<<<(512 * 128) / 256, 256, 0, stream>>>(ff_w2, 512, 128, ff2T);
    k_wT<<<(128 * 512) / 256, 256, 0, stream>>>(fc1_w, 128, 512, fc1T);

    // GCN: h = (agg @ gcn_w) * ininv + gcn_b    (bufC.region1 -> buf1)
    k_gemm<0><<<NRB, 256, 0, stream>>>(agg, gwT, buf1, 128, 128, gcn_b, ininv);
    // f = gelu(h @ ff_w1 + ff_b1)               (buf1 -> bufC, overwrites xh/agg)
    k_gemm<1><<<4 * NRB, 256, 0, stream>>>(buf1, ff1T, bufC, 128, 512, ff_b1, nullptr);
    k_ln<<<N_NODES / 4, 256, 0, stream>>>(bufC, ln_g, ln_b);
    // h2 = f @ ff_w2 + ff_b2                    (bufC -> buf1)
    k_gemm<2><<<NRB, 256, 0, stream>>>(bufC, ff2T, buf1, 512, 128, ff_b2, nullptr);
    // m1 = gelu(h2 @ fc1_w + fc1_b)             (buf1 -> bufC)
    k_gemm<1><<<4 * NRB, 256, 0, stream>>>(buf1, fc1T, bufC, 128, 512, fc1_b, nullptr);
    k_bnstat<512><<<256, 256, 0, stream>>>(bufC, bn1s, bn1q);
    k_fold<<<512 / 4, 256, 0, stream>>>(fc2_w, fc2_b, bn1_g, bn1_b, bn1s, bn1q, 512, 512, fc2T, b2p);
    // m2 = gelu(bn1(m1) @ fc2_w + fc2_b) chunked out-of-place via buf1 tmp + copy-back
    {
        const int cOff[6] = {0, 195, 390, 585, 780, 782};
        for (int c = 0; c < 5; ++c) {
            int rb0 = cOff[c], nrb = cOff[c + 1] - rb0;
            k_gemm<1><<<nrb * 4, 256, 0, stream>>>(bufC + (size_t)rb0 * 128 * 512, fc2T,
                                                   buf1, 512, 512, b2p, nullptr);
            hipMemcpyAsync(bufC + (size_t)rb0 * 128 * 512, buf1,
                           (size_t)nrb * 128 * 512 * 2, hipMemcpyDeviceToDevice, stream);
        }
    }
    k_bnstat<512><<<256, 256, 0, stream>>>(bufC, bn2s, bn2q);
    k_fold<<<128 / 4, 256, 0, stream>>>(fc3_w, fc3_b, bn2_g, bn2_b, bn2s, bn2q, 512, 128, fc3T, b3p);
    // m3 = gelu(bn2(m2) @ fc3_w + fc3_b)        (bufC -> buf1)
    k_gemm<1><<<NRB, 256, 0, stream>>>(bufC, fc3T, buf1, 512, 128, b3p, nullptr);
    k_bnstat<128><<<256, 256, 0, stream>>>(buf1, bn3s, bn3q);
    k_fold<<<1, 256, 0, stream>>>(fc4_w, fc4_b, bn3_g, bn3_b, bn3s, bn3q, 128, 1, w4t, b4p);
    k_out<<<N_NODES / 4, 256, 0, stream>>>(buf1, w4t, b4p, out);
}

// Round 4
// 801.510 us; speedup vs baseline: 1.5413x; 1.4879x over previous
//
#include <hip/hip_runtime.h>
#include <hip/hip_bf16.h>

#define N_NODES 100000
#define NPAD    100096          // 782 * 128
#define NRB     782
#define E_EDGES 1600000
#define NBLK_SCAN 98

typedef unsigned int   uint;
typedef unsigned short ushort;
typedef __attribute__((ext_vector_type(8))) short bfx8;   // 8 bf16 (4 VGPRs)
typedef __attribute__((ext_vector_type(4))) float fx4;

__device__ __forceinline__ float bf2f(ushort u) {
    return __uint_as_float(((uint)u) << 16);
}
__device__ __forceinline__ ushort f2bf(float f) {
    uint x = __float_as_uint(f);
    return (ushort)((x + 0x7FFFu + ((x >> 16) & 1u)) >> 16);   // RNE
}
__device__ __forceinline__ float gelu_erf(float x) {
    return 0.5f * x * (1.0f + erff(x * 0.70710678118654752f));
}
__device__ __forceinline__ float wave_sum(float v) {
    #pragma unroll
    for (int m = 1; m < 64; m <<= 1) v += __shfl_xor(v, m, 64);
    return v;
}

// ---------------- graph prep ----------------
__global__ void k_deg(const int* __restrict__ src, const int* __restrict__ dst,
                      int* __restrict__ outc, int* __restrict__ inc)
{
    int e = blockIdx.x * 256 + threadIdx.x;
    if (e < E_EDGES) {
        atomicAdd(&outc[src[e]], 1);
        atomicAdd(&inc[dst[e]], 1);
    }
}

__global__ void k_scales(const int* __restrict__ outc, const int* __restrict__ inc,
                         float* __restrict__ oscale, float* __restrict__ ininv)
{
    int r = blockIdx.x * 256 + threadIdx.x;
    if (r < NPAD) {
        oscale[r] = rsqrtf((float)max(outc[r], 1));
        ininv[r]  = rsqrtf((float)max(inc[r], 1));
    }
}

__global__ void k_scan1(const int* __restrict__ inc, int* __restrict__ coff, int* __restrict__ btot)
{
    __shared__ int a[1024], bsh[1024];
    int t = threadIdx.x;
    int i = blockIdx.x * 1024 + t;
    a[t] = (i < N_NODES) ? inc[i] : 0;
    __syncthreads();
    int* s = a; int* d = bsh;
    for (int dd = 1; dd < 1024; dd <<= 1) {
        int v = s[t] + ((t >= dd) ? s[t - dd] : 0);
        d[t] = v;
        __syncthreads();
        int* tmp = s; s = d; d = tmp;
    }
    if (i < N_NODES) coff[i + 1] = s[t];
    if (t == 1023) btot[blockIdx.x] = s[t];
}

__global__ void k_scan2(int* __restrict__ btot)
{
    __shared__ int a[128], bsh[128];
    int t = threadIdx.x;
    a[t] = (t < NBLK_SCAN) ? btot[t] : 0;
    __syncthreads();
    int* s = a; int* d = bsh;
    for (int dd = 1; dd < 128; dd <<= 1) {
        int v = s[t] + ((t >= dd) ? s[t - dd] : 0);
        d[t] = v;
        __syncthreads();
        int* tmp = s; s = d; d = tmp;
    }
    if (t < NBLK_SCAN) btot[t] = s[t];
}

__global__ void k_scan3(int* __restrict__ coff, const int* __restrict__ btot)
{
    int i = blockIdx.x * 256 + threadIdx.x;
    if (i == 0) coff[0] = 0;
    if (i < N_NODES) {
        int blk = i >> 10;
        if (blk > 0) coff[i + 1] += btot[blk - 1];
    }
}

__global__ void k_fill(const int* __restrict__ src, const int* __restrict__ dst,
                       const int* __restrict__ coff, int* __restrict__ cur, int* __restrict__ eidx)
{
    int e = blockIdx.x * 256 + threadIdx.x;
    if (e < E_EDGES) {
        int d = dst[e];
        int p = coff[d] + atomicAdd(&cur[d], 1);
        eidx[p] = src[e];
    }
}

// xh[r,:] = bf16(x[r,:] * oscale[r])
__global__ void k_xhat(const float* __restrict__ x, const float* __restrict__ oscale,
                       ushort* __restrict__ xh)
{
    size_t i = (size_t)blockIdx.x * 256 + threadIdx.x;
    size_t e0 = i * 4;
    int row = (int)(e0 >> 7);
    uint2 o;
    if (row < N_NODES) {
        float4 v = *(const float4*)(x + e0);
        float s = oscale[row];
        o.x = (uint)f2bf(v.x * s) | ((uint)f2bf(v.y * s) << 16);
        o.y = (uint)f2bf(v.z * s) | ((uint)f2bf(v.w * s) << 16);
    } else {
        o.x = 0u; o.y = 0u;
    }
    *(uint2*)(xh + e0) = o;
}

// one wave per dst row, 4 edges in flight, 16B/lane gather
__global__ void k_agg(const int* __restrict__ off, const int* __restrict__ eidx,
                      const ushort* __restrict__ xh, ushort* __restrict__ agg)
{
    int wid = threadIdx.x >> 6, lane = threadIdx.x & 63;
    int r = blockIdx.x * 4 + wid;
    if (r >= NPAD) return;
    int f = lane & 15;   // 16 lanes x 8 bf16 = 128 cols
    int g = lane >> 4;   // edge slot 0..3
    float a[8] = {0.f, 0.f, 0.f, 0.f, 0.f, 0.f, 0.f, 0.f};
    if (r < N_NODES) {
        int s = off[r], e = off[r + 1];
        for (int i = s + g; i < e; i += 4) {
            int sv = eidx[i];
            bfx8 v = *(const bfx8*)(xh + (size_t)sv * 128 + f * 8);
            #pragma unroll
            for (int k = 0; k < 8; ++k) a[k] += bf2f((ushort)v[k]);
        }
    }
    #pragma unroll
    for (int k = 0; k < 8; ++k) {
        a[k] += __shfl_xor(a[k], 16, 64);
        a[k] += __shfl_xor(a[k], 32, 64);
    }
    if (g == 0) {
        bfx8 o;
        #pragma unroll
        for (int k = 0; k < 8; ++k) o[k] = (short)f2bf(a[k]);
        *(bfx8*)(agg + (size_t)r * 128 + f * 8) = o;
    }
}

// transpose+convert weight [K,M] f32 -> [M,K] bf16
__global__ void k_wT(const float* __restrict__ W, int K, int M, ushort* __restrict__ Wt)
{
    int id = blockIdx.x * 256 + threadIdx.x;
    if (id < K * M) {
        int m = id / K, k = id - m * K;
        Wt[id] = f2bf(W[(size_t)k * M + m]);
    }
}

// ---------------- GEMM: C = A @ Bt^T, bf16 MFMA, optional fused BN col-stats ----
// EPI: 0 = rowscale*acc + bias, 1 = gelu(acc+bias), 2 = acc+bias
template <int EPI, int STATS>
__global__ __launch_bounds__(256, 4) void k_gemm(
    const ushort* __restrict__ A, const ushort* __restrict__ Bt,
    ushort* __restrict__ C, int K, int M,
    const float* __restrict__ bias, const float* __restrict__ rowscale,
    float* __restrict__ gsum, float* __restrict__ gsqs, int row0)
{
    __shared__ __align__(16) ushort As[128 * 64];
    __shared__ __align__(16) ushort Bs[128 * 64];
    char* AsB = (char*)As;
    char* BsB = (char*)Bs;

    const int nCB = M >> 7;
    const int cb = blockIdx.x % nCB;
    const int rb = blockIdx.x / nCB;
    const int tid = threadIdx.x;
    const int lane = tid & 63;
    const int wid = tid >> 6;
    const int m0 = (wid >> 1) * 64;
    const int n0 = (wid & 1) * 64;
    const int frl = lane & 15;
    const int kg = lane >> 4;   // 0..3

    fx4 acc[4][4] = {};

    const ushort* Arow0 = A + (size_t)(rb * 128) * K;
    const ushort* Brow0 = Bt + (size_t)(cb * 128) * K;

    for (int kb = 0; kb < K; kb += 64) {
        #pragma unroll
        for (int c = 0; c < 4; ++c) {
            int b = c * 4096 + tid * 16;     // linear byte in 16KB tile
            int row = b >> 7;                // 128B per row (64 bf16)
            int cib = b & 127;
            int swz = b ^ ((row & 7) << 4);  // XOR-swizzle 16B slots
            *(bfx8*)(AsB + swz) = *(const bfx8*)((const char*)(Arow0 + (size_t)row * K + kb) + cib);
            *(bfx8*)(BsB + swz) = *(const bfx8*)((const char*)(Brow0 + (size_t)row * K + kb) + cib);
        }
        __syncthreads();
        #pragma unroll
        for (int kk = 0; kk < 2; ++kk) {
            bfx8 av[4], bv[4];
            #pragma unroll
            for (int i = 0; i < 4; ++i) {
                int ar = m0 + i * 16 + frl;
                int ab = (ar * 128 + kk * 64 + kg * 16) ^ ((ar & 7) << 4);
                av[i] = *(const bfx8*)(AsB + ab);
                int br = n0 + i * 16 + frl;
                int bb = (br * 128 + kk * 64 + kg * 16) ^ ((br & 7) << 4);
                bv[i] = *(const bfx8*)(BsB + bb);
            }
            #pragma unroll
            for (int i = 0; i < 4; ++i)
                #pragma unroll
                for (int j = 0; j < 4; ++j)
                    acc[i][j] = __builtin_amdgcn_mfma_f32_16x16x32_bf16(av[i], bv[j], acc[i][j], 0, 0, 0);
        }
        __syncthreads();
    }

    float sL[4] = {0.f, 0.f, 0.f, 0.f}, qL[4] = {0.f, 0.f, 0.f, 0.f};
    #pragma unroll
    for (int j = 0; j < 4; ++j) {
        int col = cb * 128 + n0 + j * 16 + frl;
        float bcol = bias[col];
        #pragma unroll
        for (int i = 0; i < 4; ++i) {
            int rbase = rb * 128 + m0 + i * 16 + kg * 4;
            #pragma unroll
            for (int r = 0; r < 4; ++r) {
                float v = acc[i][j][r];
                int row = rbase + r;
                if (EPI == 0)      v = v * rowscale[row] + bcol;
                else if (EPI == 1) v = gelu_erf(v + bcol);
                else               v = v + bcol;
                C[(size_t)row * M + col] = f2bf(v);
                if (STATS) {
                    if (row0 + row < N_NODES) { sL[j] += v; qL[j] += v * v; }
                }
            }
        }
    }

    if (STATS) {
        float* cs = (float*)AsB;      // reuse LDS (K-loop done)
        float* cq = cs + 128;
        if (tid < 128) { cs[tid] = 0.f; cq[tid] = 0.f; }
        __syncthreads();
        #pragma unroll
        for (int j = 0; j < 4; ++j) {
            float s = sL[j], q = qL[j];
            s += __shfl_xor(s, 16, 64); s += __shfl_xor(s, 32, 64);
            q += __shfl_xor(q, 16, 64); q += __shfl_xor(q, 32, 64);
            if (kg == 0) {
                atomicAdd(&cs[n0 + j * 16 + frl], s);
                atomicAdd(&cq[n0 + j * 16 + frl], q);
            }
        }
        __syncthreads();
        if (tid < 128) {
            atomicAdd(&gsum[cb * 128 + tid], cs[tid]);
            atomicAdd(&gsqs[cb * 128 + tid], cq[tid]);
        }
    }
}

// in-place LayerNorm over 512 cols, one wave per row
__global__ void k_ln(ushort* __restrict__ f, const float* __restrict__ g, const float* __restrict__ b)
{
    int wid = threadIdx.x >> 6, lane = threadIdx.x & 63;
    int r = blockIdx.x * 4 + wid;
    if (r >= N_NODES) return;
    ushort* row = f + (size_t)r * 512;
    bfx8 raw = *(const bfx8*)(row + lane * 8);
    float v[8];
    float s = 0.f, q = 0.f;
    #pragma unroll
    for (int i = 0; i < 8; ++i) {
        v[i] = bf2f((ushort)raw[i]);
        s += v[i]; q += v[i] * v[i];
    }
    s = wave_sum(s); q = wave_sum(q);
    float mean = s * (1.f / 512.f);
    float var = q * (1.f / 512.f) - mean * mean;
    float sc = rsqrtf(var + 1e-5f);
    float4 g0 = *(const float4*)(g + lane * 8), g1 = *(const float4*)(g + lane * 8 + 4);
    float4 b0 = *(const float4*)(b + lane * 8), b1 = *(const float4*)(b + lane * 8 + 4);
    float gg[8] = {g0.x, g0.y, g0.z, g0.w, g1.x, g1.y, g1.z, g1.w};
    float bb[8] = {b0.x, b0.y, b0.z, b0.w, b1.x, b1.y, b1.z, b1.w};
    bfx8 o;
    #pragma unroll
    for (int i = 0; i < 8; ++i) o[i] = (short)f2bf((v[i] - mean) * sc * gg[i] + bb[i]);
    *(bfx8*)(row + lane * 8) = o;
}

// fold BN(prev-layer cols) into next weight
__global__ void k_fold(const float* __restrict__ W, const float* __restrict__ bw,
                       const float* __restrict__ g, const float* __restrict__ bb,
                       const float* __restrict__ sum, const float* __restrict__ sqs,
                       int K, int M, ushort* __restrict__ WtO, float* __restrict__ bO)
{
    int wid = threadIdx.x >> 6, lane = threadIdx.x & 63;
    int m = blockIdx.x * 4 + wid;
    if (m >= M) return;
    float acc = 0.f;
    for (int k = lane; k < K; k += 64) {
        float mean = sum[k] * (1.f / (float)N_NODES);
        float var = sqs[k] * (1.f / (float)N_NODES) - mean * mean;
        float s = g[k] * rsqrtf(var + 1e-5f);
        float t = bb[k] - mean * s;
        float w = W[(size_t)k * M + m];
        WtO[(size_t)m * K + k] = f2bf(w * s);
        acc += t * w;
    }
    acc = wave_sum(acc);
    if (lane == 0) bO[m] = bw[m] + acc;
}

// out[r] = dot(m3[r,:128], w4) + b4
__global__ void k_out(const ushort* __restrict__ m3, const ushort* __restrict__ w4,
                      const float* __restrict__ b4, float* __restrict__ out)
{
    int wid = threadIdx.x >> 6, lane = threadIdx.x & 63;
    int r = blockIdx.x * 4 + wid;
    if (r >= N_NODES) return;
    uint u = *(const uint*)(m3 + (size_t)r * 128 + lane * 2);
    uint w = *(const uint*)(w4 + lane * 2);
    float acc = bf2f((ushort)(u & 0xffffu)) * bf2f((ushort)(w & 0xffffu))
              + bf2f((ushort)(u >> 16)) * bf2f((ushort)(w >> 16));
    acc = wave_sum(acc);
    if (lane == 0) out[r] = acc + b4[0];
}

extern "C" void kernel_launch(void* const* d_in, const int* in_sizes, int n_in,
                              void* d_out, int out_size, void* d_ws, size_t ws_size,
                              hipStream_t stream)
{
    const float* x     = (const float*)d_in[0];
    const int*   src   = (const int*)d_in[1];
    const int*   dst   = (const int*)d_in[2];
    const float* gcn_w = (const float*)d_in[3];
    const float* gcn_b = (const float*)d_in[4];
    const float* ff_w1 = (const float*)d_in[5];
    const float* ff_b1 = (const float*)d_in[6];
    const float* ln_g  = (const float*)d_in[7];
    const float* ln_b  = (const float*)d_in[8];
    const float* ff_w2 = (const float*)d_in[9];
    const float* ff_b2 = (const float*)d_in[10];
    const float* fc1_w = (const float*)d_in[11];
    const float* fc1_b = (const float*)d_in[12];
    const float* bn1_g = (const float*)d_in[13];
    const float* bn1_b = (const float*)d_in[14];
    const float* fc2_w = (const float*)d_in[15];
    const float* fc2_b = (const float*)d_in[16];
    const float* bn2_g = (const float*)d_in[17];
    const float* bn2_b = (const float*)d_in[18];
    const float* fc3_w = (const float*)d_in[19];
    const float* fc3_b = (const float*)d_in[20];
    const float* bn3_g = (const float*)d_in[21];
    const float* bn3_b = (const float*)d_in[22];
    const float* fc4_w = (const float*)d_in[23];
    const float* fc4_b = (const float*)d_in[24];
    float* out = (float*)d_out;
    (void)in_sizes; (void)n_in; (void)out_size;

    char* base = (char*)d_ws;
    char* p = base;
    auto alloc = [&](size_t bytes) -> char* {
        char* r = p;
        p += (bytes + 255) & ~(size_t)255;
        return r;
    };
    int*    outc   = (int*)alloc((size_t)NPAD * 4);
    int*    inc    = (int*)alloc((size_t)NPAD * 4);
    int*    cur    = (int*)alloc((size_t)NPAD * 4);
    int*    coff   = (int*)alloc(((size_t)NPAD + 1) * 4);
    int*    btot   = (int*)alloc(128 * 4);
    int*    eidx   = (int*)alloc((size_t)E_EDGES * 4);
    float*  oscale = (float*)alloc((size_t)NPAD * 4);
    float*  ininv  = (float*)alloc((size_t)NPAD * 4);
    float*  bns    = (float*)alloc(6 * 512 * 4);
    float*  b2p    = (float*)alloc(512 * 4);
    float*  b3p    = (float*)alloc(128 * 4);
    float*  b4p    = (float*)alloc(4);
    ushort* gwT    = (ushort*)alloc(128 * 128 * 2);
    ushort* ff1T   = (ushort*)alloc(512 * 128 * 2);
    ushort* ff2T   = (ushort*)alloc(128 * 512 * 2);
    ushort* fc1T   = (ushort*)alloc(512 * 128 * 2);
    ushort* fc2T   = (ushort*)alloc(512 * 512 * 2);
    ushort* fc3T   = (ushort*)alloc(128 * 512 * 2);
    ushort* w4t    = (ushort*)alloc(128 * 2);
    ushort* buf1   = (ushort*)alloc((size_t)NPAD * 128 * 2);  // h -> h2 -> (fc2 tmp) -> m3
    ushort* bufC   = (ushort*)alloc((size_t)NPAD * 512 * 2);  // xh+agg -> f(+LN) -> m1 [-> m2]

    // optional separate m2 buffer if workspace allows (kills fc2 copy-backs)
    size_t used = (size_t)(p - base);
    bool   sep  = (used + (size_t)NPAD * 512 * 2) <= ws_size;
    ushort* m2  = sep ? (ushort*)alloc((size_t)NPAD * 512 * 2) : bufC;

    ushort* xh  = bufC;                          // [NPAD,128] region 0
    ushort* agg = bufC + (size_t)NPAD * 128;     // [NPAD,128] region 1

    float* bn1s = bns;
    float* bn1q = bns + 512;
    float* bn2s = bns + 1024;
    float* bn2q = bns + 1536;
    float* bn3s = bns + 2048;
    float* bn3q = bns + 2560;

    hipMemsetAsync(outc, 0, (size_t)NPAD * 4, stream);
    hipMemsetAsync(inc, 0, (size_t)NPAD * 4, stream);
    hipMemsetAsync(cur, 0, (size_t)NPAD * 4, stream);
    hipMemsetAsync(bns, 0, 6 * 512 * 4, stream);

    k_deg<<<E_EDGES / 256, 256, 0, stream>>>(src, dst, outc, inc);
    k_scales<<<NPAD / 256, 256, 0, stream>>>(outc, inc, oscale, ininv);
    k_scan1<<<NBLK_SCAN, 1024, 0, stream>>>(inc, coff, btot);
    k_scan2<<<1, 128, 0, stream>>>(btot);
    k_scan3<<<(N_NODES + 255) / 256, 256, 0, stream>>>(coff, btot);
    k_fill<<<E_EDGES / 256, 256, 0, stream>>>(src, dst, coff, cur, eidx);
    k_xhat<<<(NPAD / 256) * 32, 256, 0, stream>>>(x, oscale, xh);
    k_agg<<<NPAD / 4, 256, 0, stream>>>(coff, eidx, xh, agg);

    k_wT<<<(128 * 128) / 256, 256, 0, stream>>>(gcn_w, 128, 128, gwT);
    k_wT<<<(128 * 512) / 256, 256, 0, stream>>>(ff_w1, 128, 512, ff1T);
    k_wT<<<(512 * 128) / 256, 256, 0, stream>>>(ff_w2, 512, 128, ff2T);
    k_wT<<<(128 * 512) / 256, 256, 0, stream>>>(fc1_w, 128, 512, fc1T);

    // GCN: h = (agg @ gcn_w) * ininv + gcn_b    (bufC.region1 -> buf1)
    k_gemm<0, 0><<<NRB, 256, 0, stream>>>(agg, gwT, buf1, 128, 128, gcn_b, ininv, nullptr, nullptr, 0);
    // f = gelu(h @ ff_w1 + ff_b1)               (buf1 -> bufC)
    k_gemm<1, 0><<<4 * NRB, 256, 0, stream>>>(buf1, ff1T, bufC, 128, 512, ff_b1, nullptr, nullptr, nullptr, 0);
    k_ln<<<N_NODES / 4, 256, 0, stream>>>(bufC, ln_g, ln_b);
    // h2 = f @ ff_w2 + ff_b2                    (bufC -> buf1)
    k_gemm<2, 0><<<NRB, 256, 0, stream>>>(bufC, ff2T, buf1, 512, 128, ff_b2, nullptr, nullptr, nullptr, 0);
    // m1 = gelu(h2 @ fc1_w + fc1_b), fused bn1 stats   (buf1 -> bufC)
    k_gemm<1, 1><<<4 * NRB, 256, 0, stream>>>(buf1, fc1T, bufC, 128, 512, fc1_b, nullptr, bn1s, bn1q, 0);
    k_fold<<<512 / 4, 256, 0, stream>>>(fc2_w, fc2_b, bn1_g, bn1_b, bn1s, bn1q, 512, 512, fc2T, b2p);
    // m2 = gelu(bn1(m1) @ fc2_w + fc2_b), fused bn2 stats
    if (sep) {
        k_gemm<1, 1><<<4 * NRB, 256, 0, stream>>>(bufC, fc2T, m2, 512, 512, b2p, nullptr, bn2s, bn2q, 0);
    } else {
        const int cOff[6] = {0, 195, 390, 585, 780, 782};
        for (int c = 0; c < 5; ++c) {
            int rb0 = cOff[c], nrb = cOff[c + 1] - rb0;
            k_gemm<1, 1><<<nrb * 4, 256, 0, stream>>>(bufC + (size_t)rb0 * 128 * 512, fc2T,
                                                      buf1, 512, 512, b2p, nullptr, bn2s, bn2q, rb0 * 128);
            hipMemcpyAsync(bufC + (size_t)rb0 * 128 * 512, buf1,
                           (size_t)nrb * 128 * 512 * 2, hipMemcpyDeviceToDevice, stream);
        }
    }
    k_fold<<<128 / 4, 256, 0, stream>>>(fc3_w, fc3_b, bn2_g, bn2_b, bn2s, bn2q, 512, 128, fc3T, b3p);
    // m3 = gelu(bn2(m2) @ fc3_w + fc3_b), fused bn3 stats   (m2 -> buf1)
    k_gemm<1, 1><<<NRB, 256, 0, stream>>>(m2, fc3T, buf1, 512, 128, b3p, nullptr, bn3s, bn3q, 0);
    k_fold<<<1, 256, 0, stream>>>(fc4_w, fc4_b, bn3_g, bn3_b, bn3s, bn3q, 128, 1, w4t, b4p);
    k_out<<<N_NODES / 4, 256, 0, stream>>>(buf1, w4t, b4p, out);
}

// Round 5
// 703.817 us; speedup vs baseline: 1.7553x; 1.1388x over previous
//
#include <hip/hip_runtime.h>
#include <hip/hip_bf16.h>

#define N_NODES 100000
#define NPAD    100096          // 782 * 128
#define NRB     782
#define E_EDGES 1600000
#define NBLK_SCAN 98

#define AS1 __attribute__((address_space(1)))
#define AS3 __attribute__((address_space(3)))

typedef unsigned int   uint;
typedef unsigned short ushort;
typedef __attribute__((ext_vector_type(8))) short bfx8;   // 8 bf16 (4 VGPRs)
typedef __attribute__((ext_vector_type(4))) float fx4;

__device__ __forceinline__ float bf2f(ushort u) {
    return __uint_as_float(((uint)u) << 16);
}
__device__ __forceinline__ ushort f2bf(float f) {
    uint x = __float_as_uint(f);
    return (ushort)((x + 0x7FFFu + ((x >> 16) & 1u)) >> 16);   // RNE
}
// tanh-GELU == x * sigmoid(1.5957691*(x + 0.044715 x^3)); |diff vs erf-GELU| <= ~3e-3
__device__ __forceinline__ float gelu_fast(float x) {
    float u = 1.5957691f * __builtin_fmaf(0.044715f * x * x, x, x);
    return x / (1.0f + __expf(-u));
}
__device__ __forceinline__ float wave_sum(float v) {
    #pragma unroll
    for (int m = 1; m < 64; m <<= 1) v += __shfl_xor(v, m, 64);
    return v;
}
// bijective XCD swizzle (m204): blocks on the same XCD get contiguous wgids
__device__ __forceinline__ int xcd_swz(int orig, int nwg) {
    int q = nwg >> 3, r = nwg & 7;
    int x = orig & 7, o = orig >> 3;
    return (x < r ? x * (q + 1) : r * (q + 1) + (x - r) * q) + o;
}

// ---------------- graph prep ----------------
__global__ void k_deg(const int* __restrict__ src, const int* __restrict__ dst,
                      int* __restrict__ outc, int* __restrict__ inc)
{
    int e = blockIdx.x * 256 + threadIdx.x;
    if (e < E_EDGES) {
        atomicAdd(&outc[src[e]], 1);
        atomicAdd(&inc[dst[e]], 1);
    }
}

__global__ void k_scales(const int* __restrict__ outc, const int* __restrict__ inc,
                         float* __restrict__ oscale, float* __restrict__ ininv)
{
    int r = blockIdx.x * 256 + threadIdx.x;
    if (r < NPAD) {
        oscale[r] = rsqrtf((float)max(outc[r], 1));
        ininv[r]  = rsqrtf((float)max(inc[r], 1));
    }
}

__global__ void k_scan1(const int* __restrict__ inc, int* __restrict__ coff, int* __restrict__ btot)
{
    __shared__ int a[1024], bsh[1024];
    int t = threadIdx.x;
    int i = blockIdx.x * 1024 + t;
    a[t] = (i < N_NODES) ? inc[i] : 0;
    __syncthreads();
    int* s = a; int* d = bsh;
    for (int dd = 1; dd < 1024; dd <<= 1) {
        int v = s[t] + ((t >= dd) ? s[t - dd] : 0);
        d[t] = v;
        __syncthreads();
        int* tmp = s; s = d; d = tmp;
    }
    if (i < N_NODES) coff[i + 1] = s[t];
    if (t == 1023) btot[blockIdx.x] = s[t];
}

__global__ void k_scan2(int* __restrict__ btot)
{
    __shared__ int a[128], bsh[128];
    int t = threadIdx.x;
    a[t] = (t < NBLK_SCAN) ? btot[t] : 0;
    __syncthreads();
    int* s = a; int* d = bsh;
    for (int dd = 1; dd < 128; dd <<= 1) {
        int v = s[t] + ((t >= dd) ? s[t - dd] : 0);
        d[t] = v;
        __syncthreads();
        int* tmp = s; s = d; d = tmp;
    }
    if (t < NBLK_SCAN) btot[t] = s[t];
}

__global__ void k_scan3(int* __restrict__ coff, const int* __restrict__ btot)
{
    int i = blockIdx.x * 256 + threadIdx.x;
    if (i == 0) coff[0] = 0;
    if (i < N_NODES) {
        int blk = i >> 10;
        if (blk > 0) coff[i + 1] += btot[blk - 1];
    }
}

__global__ void k_fill(const int* __restrict__ src, const int* __restrict__ dst,
                       const int* __restrict__ coff, int* __restrict__ cur, int* __restrict__ eidx)
{
    int e = blockIdx.x * 256 + threadIdx.x;
    if (e < E_EDGES) {
        int d = dst[e];
        int p = coff[d] + atomicAdd(&cur[d], 1);
        eidx[p] = src[e];
    }
}

// xh[r,:] = bf16(x[r,:] * oscale[r])
__global__ void k_xhat(const float* __restrict__ x, const float* __restrict__ oscale,
                       ushort* __restrict__ xh)
{
    size_t i = (size_t)blockIdx.x * 256 + threadIdx.x;
    size_t e0 = i * 4;
    int row = (int)(e0 >> 7);
    uint2 o;
    if (row < N_NODES) {
        float4 v = *(const float4*)(x + e0);
        float s = oscale[row];
        o.x = (uint)f2bf(v.x * s) | ((uint)f2bf(v.y * s) << 16);
        o.y = (uint)f2bf(v.z * s) | ((uint)f2bf(v.w * s) << 16);
    } else {
        o.x = 0u; o.y = 0u;
    }
    *(uint2*)(xh + e0) = o;
}

// one wave per dst row, 4 edges in flight, 16B/lane gather
__global__ void k_agg(const int* __restrict__ off, const int* __restrict__ eidx,
                      const ushort* __restrict__ xh, ushort* __restrict__ agg)
{
    int wid = threadIdx.x >> 6, lane = threadIdx.x & 63;
    int r = blockIdx.x * 4 + wid;
    if (r >= NPAD) return;
    int f = lane & 15;   // 16 lanes x 8 bf16 = 128 cols
    int g = lane >> 4;   // edge slot 0..3
    float a[8] = {0.f, 0.f, 0.f, 0.f, 0.f, 0.f, 0.f, 0.f};
    if (r < N_NODES) {
        int s = off[r], e = off[r + 1];
        for (int i = s + g; i < e; i += 4) {
            int sv = eidx[i];
            bfx8 v = *(const bfx8*)(xh + (size_t)sv * 128 + f * 8);
            #pragma unroll
            for (int k = 0; k < 8; ++k) a[k] += bf2f((ushort)v[k]);
        }
    }
    #pragma unroll
    for (int k = 0; k < 8; ++k) {
        a[k] += __shfl_xor(a[k], 16, 64);
        a[k] += __shfl_xor(a[k], 32, 64);
    }
    if (g == 0) {
        bfx8 o;
        #pragma unroll
        for (int k = 0; k < 8; ++k) o[k] = (short)f2bf(a[k]);
        *(bfx8*)(agg + (size_t)r * 128 + f * 8) = o;
    }
}

// transpose+convert weight [K,M] f32 -> [M,K] bf16
__global__ void k_wT(const float* __restrict__ W, int K, int M, ushort* __restrict__ Wt)
{
    int id = blockIdx.x * 256 + threadIdx.x;
    if (id < K * M) {
        int m = id / K, k = id - m * K;
        Wt[id] = f2bf(W[(size_t)k * M + m]);
    }
}

// ---------------- GEMM: C = A @ Bt^T, bf16 MFMA ----------------
// global_load_lds staging (linear LDS dest, inverse-swizzled global source,
// swizzled ds_read), LDS-staged coalesced epilogue, optional fused BN stats.
// EPI: 0 = rowscale*acc + bias, 1 = gelu(acc+bias), 2 = acc+bias
template <int EPI, int STATS>
__global__ __launch_bounds__(256, 4) void k_gemm(
    const ushort* __restrict__ A, const ushort* __restrict__ Bt,
    ushort* __restrict__ C, int K, int M,
    const float* __restrict__ bias, const float* __restrict__ rowscale,
    float* __restrict__ gsum, float* __restrict__ gsqs, int row0)
{
    __shared__ __align__(16) char smem[32768 + (STATS ? 1024 : 0)];
    char* AsB = smem;            // 16 KB A tile (K-loop) | epilogue: C tile 32 KB
    char* BsB = smem + 16384;    // 16 KB B tile

    const int nwg = gridDim.x;
    const int wgid = xcd_swz(blockIdx.x, nwg);
    const int nCB = M >> 7;
    const int cb = wgid % nCB;
    const int rb = wgid / nCB;
    const int tid = threadIdx.x;
    const int lane = tid & 63;
    const int wid = tid >> 6;
    const int m0 = (wid >> 1) * 64;
    const int n0 = (wid & 1) * 64;
    const int frl = lane & 15;
    const int kg = lane >> 4;   // 0..3

    float* statsf = (float*)(smem + 32768);
    if (STATS && tid < 128) { statsf[tid] = 0.f; statsf[128 + tid] = 0.f; }

    fx4 acc[4][4] = {};

    const ushort* Arow0 = A + (size_t)(rb * 128) * K;
    const ushort* Brow0 = Bt + (size_t)(cb * 128) * K;

    for (int kb = 0; kb < K; kb += 64) {
        #pragma unroll
        for (int c = 0; c < 4; ++c) {
            int b = c * 4096 + tid * 16;                 // linear LDS byte
            int row = b >> 7;                            // 128B per row
            int cibs = (b & 127) ^ ((row & 7) << 4);     // inverse-swizzled source
            const char* ga = (const char*)(Arow0 + (size_t)row * K + kb) + cibs;
            const char* gb = (const char*)(Brow0 + (size_t)row * K + kb) + cibs;
            char* la = AsB + c * 4096 + (wid << 10);     // wave-uniform base (+lane*16 by HW)
            char* lb = BsB + c * 4096 + (wid << 10);
            __builtin_amdgcn_global_load_lds((const AS1 void*)ga, (AS3 void*)la, 16, 0, 0);
            __builtin_amdgcn_global_load_lds((const AS1 void*)gb, (AS3 void*)lb, 16, 0, 0);
        }
        __syncthreads();
        #pragma unroll
        for (int kk = 0; kk < 2; ++kk) {
            bfx8 av[4], bv[4];
            #pragma unroll
            for (int i = 0; i < 4; ++i) {
                int ar = m0 + i * 16 + frl;
                int ab = (ar * 128 + kk * 64 + kg * 16) ^ ((ar & 7) << 4);
                av[i] = *(const bfx8*)(AsB + ab);
                int br = n0 + i * 16 + frl;
                int bb = (br * 128 + kk * 64 + kg * 16) ^ ((br & 7) << 4);
                bv[i] = *(const bfx8*)(BsB + bb);
            }
            #pragma unroll
            for (int i = 0; i < 4; ++i)
                #pragma unroll
                for (int j = 0; j < 4; ++j)
                    acc[i][j] = __builtin_amdgcn_mfma_f32_16x16x32_bf16(av[i], bv[j], acc[i][j], 0, 0, 0);
        }
        __syncthreads();
    }

    // ---- epilogue: epi + stats + LDS C-tile (swizzled b16 writes) ----
    float sL[4] = {0.f, 0.f, 0.f, 0.f}, qL[4] = {0.f, 0.f, 0.f, 0.f};
    #pragma unroll
    for (int j = 0; j < 4; ++j) {
        int colL = n0 + j * 16 + frl;
        float bcol = bias[cb * 128 + colL];
        #pragma unroll
        for (int i = 0; i < 4; ++i) {
            int rbaseL = m0 + i * 16 + kg * 4;
            #pragma unroll
            for (int r = 0; r < 4; ++r) {
                float v = acc[i][j][r];
                int rowL = rbaseL + r;
                if (EPI == 0)      v = v * rowscale[rb * 128 + rowL] + bcol;
                else if (EPI == 1) v = gelu_fast(v + bcol);
                else               v = v + bcol;
                if (STATS) {
                    if (row0 + rb * 128 + rowL < N_NODES) { sL[j] += v; qL[j] += v * v; }
                }
                int boff = rowL * 256 + ((colL * 2) ^ ((rowL & 7) << 4));
                *(ushort*)(smem + boff) = f2bf(v);
            }
        }
    }
    if (STATS) {
        #pragma unroll
        for (int j = 0; j < 4; ++j) {
            float s = sL[j], q = qL[j];
            s += __shfl_xor(s, 16, 64); s += __shfl_xor(s, 32, 64);
            q += __shfl_xor(q, 16, 64); q += __shfl_xor(q, 32, 64);
            if (kg == 0) {
                atomicAdd(&statsf[n0 + j * 16 + frl], s);
                atomicAdd(&statsf[128 + n0 + j * 16 + frl], q);
            }
        }
    }
    __syncthreads();
    // coalesced global write: 16 lanes x 16B = 256B per row
    {
        int r2 = tid >> 4;            // 0..15
        int s2 = tid & 15;
        #pragma unroll
        for (int pass = 0; pass < 8; ++pass) {
            int rowL = pass * 16 + r2;
            int boff = rowL * 256 + ((s2 * 16) ^ ((rowL & 7) << 4));
            bfx8 v = *(const bfx8*)(smem + boff);
            *(bfx8*)((char*)(C + (size_t)(rb * 128 + rowL) * M + cb * 128) + s2 * 16) = v;
        }
    }
    if (STATS && tid < 128) {
        atomicAdd(&gsum[cb * 128 + tid], statsf[tid]);
        atomicAdd(&gsqs[cb * 128 + tid], statsf[128 + tid]);
    }
}

// in-place LayerNorm over 512 cols, one wave per row
__global__ void k_ln(ushort* __restrict__ f, const float* __restrict__ g, const float* __restrict__ b)
{
    int wid = threadIdx.x >> 6, lane = threadIdx.x & 63;
    int r = blockIdx.x * 4 + wid;
    if (r >= N_NODES) return;
    ushort* row = f + (size_t)r * 512;
    bfx8 raw = *(const bfx8*)(row + lane * 8);
    float v[8];
    float s = 0.f, q = 0.f;
    #pragma unroll
    for (int i = 0; i < 8; ++i) {
        v[i] = bf2f((ushort)raw[i]);
        s += v[i]; q += v[i] * v[i];
    }
    s = wave_sum(s); q = wave_sum(q);
    float mean = s * (1.f / 512.f);
    float var = q * (1.f / 512.f) - mean * mean;
    float sc = rsqrtf(var + 1e-5f);
    float4 g0 = *(const float4*)(g + lane * 8), g1 = *(const float4*)(g + lane * 8 + 4);
    float4 b0 = *(const float4*)(b + lane * 8), b1 = *(const float4*)(b + lane * 8 + 4);
    float gg[8] = {g0.x, g0.y, g0.z, g0.w, g1.x, g1.y, g1.z, g1.w};
    float bb[8] = {b0.x, b0.y, b0.z, b0.w, b1.x, b1.y, b1.z, b1.w};
    bfx8 o;
    #pragma unroll
    for (int i = 0; i < 8; ++i) o[i] = (short)f2bf((v[i] - mean) * sc * gg[i] + bb[i]);
    *(bfx8*)(row + lane * 8) = o;
}

// fold BN(prev-layer cols) into next weight
__global__ void k_fold(const float* __restrict__ W, const float* __restrict__ bw,
                       const float* __restrict__ g, const float* __restrict__ bb,
                       const float* __restrict__ sum, const float* __restrict__ sqs,
                       int K, int M, ushort* __restrict__ WtO, float* __restrict__ bO)
{
    int wid = threadIdx.x >> 6, lane = threadIdx.x & 63;
    int m = blockIdx.x * 4 + wid;
    if (m >= M) return;
    float acc = 0.f;
    for (int k = lane; k < K; k += 64) {
        float mean = sum[k] * (1.f / (float)N_NODES);
        float var = sqs[k] * (1.f / (float)N_NODES) - mean * mean;
        float s = g[k] * rsqrtf(var + 1e-5f);
        float t = bb[k] - mean * s;
        float w = W[(size_t)k * M + m];
        WtO[(size_t)m * K + k] = f2bf(w * s);
        acc += t * w;
    }
    acc = wave_sum(acc);
    if (lane == 0) bO[m] = bw[m] + acc;
}

// out[r] = dot(m3[r,:128], w4) + b4
__global__ void k_out(const ushort* __restrict__ m3, const ushort* __restrict__ w4,
                      const float* __restrict__ b4, float* __restrict__ out)
{
    int wid = threadIdx.x >> 6, lane = threadIdx.x & 63;
    int r = blockIdx.x * 4 + wid;
    if (r >= N_NODES) return;
    uint u = *(const uint*)(m3 + (size_t)r * 128 + lane * 2);
    uint w = *(const uint*)(w4 + lane * 2);
    float acc = bf2f((ushort)(u & 0xffffu)) * bf2f((ushort)(w & 0xffffu))
              + bf2f((ushort)(u >> 16)) * bf2f((ushort)(w >> 16));
    acc = wave_sum(acc);
    if (lane == 0) out[r] = acc + b4[0];
}

extern "C" void kernel_launch(void* const* d_in, const int* in_sizes, int n_in,
                              void* d_out, int out_size, void* d_ws, size_t ws_size,
                              hipStream_t stream)
{
    const float* x     = (const float*)d_in[0];
    const int*   src   = (const int*)d_in[1];
    const int*   dst   = (const int*)d_in[2];
    const float* gcn_w = (const float*)d_in[3];
    const float* gcn_b = (const float*)d_in[4];
    const float* ff_w1 = (const float*)d_in[5];
    const float* ff_b1 = (const float*)d_in[6];
    const float* ln_g  = (const float*)d_in[7];
    const float* ln_b  = (const float*)d_in[8];
    const float* ff_w2 = (const float*)d_in[9];
    const float* ff_b2 = (const float*)d_in[10];
    const float* fc1_w = (const float*)d_in[11];
    const float* fc1_b = (const float*)d_in[12];
    const float* bn1_g = (const float*)d_in[13];
    const float* bn1_b = (const float*)d_in[14];
    const float* fc2_w = (const float*)d_in[15];
    const float* fc2_b = (const float*)d_in[16];
    const float* bn2_g = (const float*)d_in[17];
    const float* bn2_b = (const float*)d_in[18];
    const float* fc3_w = (const float*)d_in[19];
    const float* fc3_b = (const float*)d_in[20];
    const float* bn3_g = (const float*)d_in[21];
    const float* bn3_b = (const float*)d_in[22];
    const float* fc4_w = (const float*)d_in[23];
    const float* fc4_b = (const float*)d_in[24];
    float* out = (float*)d_out;
    (void)in_sizes; (void)n_in; (void)out_size;

    char* base = (char*)d_ws;
    char* p = base;
    auto alloc = [&](size_t bytes) -> char* {
        char* r = p;
        p += (bytes + 255) & ~(size_t)255;
        return r;
    };
    int*    outc   = (int*)alloc((size_t)NPAD * 4);
    int*    inc    = (int*)alloc((size_t)NPAD * 4);
    int*    cur    = (int*)alloc((size_t)NPAD * 4);
    int*    coff   = (int*)alloc(((size_t)NPAD + 1) * 4);
    int*    btot   = (int*)alloc(128 * 4);
    int*    eidx   = (int*)alloc((size_t)E_EDGES * 4);
    float*  oscale = (float*)alloc((size_t)NPAD * 4);
    float*  ininv  = (float*)alloc((size_t)NPAD * 4);
    float*  bns    = (float*)alloc(6 * 512 * 4);
    float*  b2p    = (float*)alloc(512 * 4);
    float*  b3p    = (float*)alloc(128 * 4);
    float*  b4p    = (float*)alloc(4);
    ushort* gwT    = (ushort*)alloc(128 * 128 * 2);
    ushort* ff1T   = (ushort*)alloc(512 * 128 * 2);
    ushort* ff2T   = (ushort*)alloc(128 * 512 * 2);
    ushort* fc1T   = (ushort*)alloc(512 * 128 * 2);
    ushort* fc2T   = (ushort*)alloc(512 * 512 * 2);
    ushort* fc3T   = (ushort*)alloc(128 * 512 * 2);
    ushort* w4t    = (ushort*)alloc(128 * 2);
    ushort* buf1   = (ushort*)alloc((size_t)NPAD * 128 * 2);  // h -> h2 -> (fc2 tmp) -> m3
    ushort* bufC   = (ushort*)alloc((size_t)NPAD * 512 * 2);  // xh+agg -> f(+LN) -> m1 [-> m2]

    // optional separate m2 buffer if workspace allows (kills fc2 copy-backs)
    size_t used = (size_t)(p - base);
    bool   sep  = (used + (size_t)NPAD * 512 * 2) <= ws_size;
    ushort* m2  = sep ? (ushort*)alloc((size_t)NPAD * 512 * 2) : bufC;

    ushort* xh  = bufC;                          // [NPAD,128] region 0
    ushort* agg = bufC + (size_t)NPAD * 128;     // [NPAD,128] region 1

    float* bn1s = bns;
    float* bn1q = bns + 512;
    float* bn2s = bns + 1024;
    float* bn2q = bns + 1536;
    float* bn3s = bns + 2048;
    float* bn3q = bns + 2560;

    hipMemsetAsync(outc, 0, (size_t)NPAD * 4, stream);
    hipMemsetAsync(inc, 0, (size_t)NPAD * 4, stream);
    hipMemsetAsync(cur, 0, (size_t)NPAD * 4, stream);
    hipMemsetAsync(bns, 0, 6 * 512 * 4, stream);

    k_deg<<<E_EDGES / 256, 256, 0, stream>>>(src, dst, outc, inc);
    k_scales<<<NPAD / 256, 256, 0, stream>>>(outc, inc, oscale, ininv);
    k_scan1<<<NBLK_SCAN, 1024, 0, stream>>>(inc, coff, btot);
    k_scan2<<<1, 128, 0, stream>>>(btot);
    k_scan3<<<(N_NODES + 255) / 256, 256, 0, stream>>>(coff, btot);
    k_fill<<<E_EDGES / 256, 256, 0, stream>>>(src, dst, coff, cur, eidx);
    k_xhat<<<(NPAD / 256) * 32, 256, 0, stream>>>(x, oscale, xh);
    k_agg<<<NPAD / 4, 256, 0, stream>>>(coff, eidx, xh, agg);

    k_wT<<<(128 * 128) / 256, 256, 0, stream>>>(gcn_w, 128, 128, gwT);
    k_wT<<<(128 * 512) / 256, 256, 0, stream>>>(ff_w1, 128, 512, ff1T);
    k_wT<<<(512 * 128) / 256, 256, 0, stream>>>(ff_w2, 512, 128, ff2T);
    k_wT<<<(128 * 512) / 256, 256, 0, stream>>>(fc1_w, 128, 512, fc1T);

    // GCN: h = (agg @ gcn_w) * ininv + gcn_b    (bufC.region1 -> buf1)
    k_gemm<0, 0><<<NRB, 256, 0, stream>>>(agg, gwT, buf1, 128, 128, gcn_b, ininv, nullptr, nullptr, 0);
    // f = gelu(h @ ff_w1 + ff_b1)               (buf1 -> bufC)
    k_gemm<1, 0><<<4 * NRB, 256, 0, stream>>>(buf1, ff1T, bufC, 128, 512, ff_b1, nullptr, nullptr, nullptr, 0);
    k_ln<<<N_NODES / 4, 256, 0, stream>>>(bufC, ln_g, ln_b);
    // h2 = f @ ff_w2 + ff_b2                    (bufC -> buf1)
    k_gemm<2, 0><<<NRB, 256, 0, stream>>>(bufC, ff2T, buf1, 512, 128, ff_b2, nullptr, nullptr, nullptr, 0);
    // m1 = gelu(h2 @ fc1_w + fc1_b), fused bn1 stats   (buf1 -> bufC)
    k_gemm<1, 1><<<4 * NRB, 256, 0, stream>>>(buf1, fc1T, bufC, 128, 512, fc1_b, nullptr, bn1s, bn1q, 0);
    k_fold<<<512 / 4, 256, 0, stream>>>(fc2_w, fc2_b, bn1_g, bn1_b, bn1s, bn1q, 512, 512, fc2T, b2p);
    // m2 = gelu(bn1(m1) @ fc2_w + fc2_b), fused bn2 stats
    if (sep) {
        k_gemm<1, 1><<<4 * NRB, 256, 0, stream>>>(bufC, fc2T, m2, 512, 512, b2p, nullptr, bn2s, bn2q, 0);
    } else {
        const int cOff[6] = {0, 195, 390, 585, 780, 782};
        for (int c = 0; c < 5; ++c) {
            int rb0 = cOff[c], nrb = cOff[c + 1] - rb0;
            k_gemm<1, 1><<<nrb * 4, 256, 0, stream>>>(bufC + (size_t)rb0 * 128 * 512, fc2T,
                                                      buf1, 512, 512, b2p, nullptr, bn2s, bn2q, rb0 * 128);
            hipMemcpyAsync(bufC + (size_t)rb0 * 128 * 512, buf1,
                           (size_t)nrb * 128 * 512 * 2, hipMemcpyDeviceToDevice, stream);
        }
    }
    k_fold<<<128 / 4, 256, 0, stream>>>(fc3_w, fc3_b, bn2_g, bn2_b, bn2s, bn2q, 512, 128, fc3T, b3p);
    // m3 = gelu(bn2(m2) @ fc3_w + fc3_b), fused bn3 stats   (m2 -> buf1)
    k_gemm<1, 1><<<NRB, 256, 0, stream>>>(m2, fc3T, buf1, 512, 128, b3p, nullptr, bn3s, bn3q, 0);
    k_fold<<<1, 256, 0, stream>>>(fc4_w, fc4_b, bn3_g, bn3_b, bn3s, bn3q, 128, 1, w4t, b4p);
    k_out<<<N_NODES / 4, 256, 0, stream>>>(buf1, w4t, b4p, out);
}